// Round 7
// baseline (121.031 us; speedup 1.0000x reference)
//
#include <hip/hip_runtime.h>

// All-pairs edge MLP, N_E=1024, NIN=64, HID=128, OUT=64, fp32.
// out[i] = ((1/1023) * sum_{k!=i} tanh(A[i]+B[k])) @ W2 + b2
//   A = x@W1[:64,:],  B = x@W1[64:,:] + b1
// Rank-separated tanh via 2D Chebyshev (P=30, domain [-5.5,5.5]^2):
//   sum_k tanh(a_i+b_k) = sum_p T_p(a_i) V_p[h],  V = C @ M,
//   M_q[h] = sum_k T_q(b_k[h]).
//
// R11: minimal 2-node graph, no atomics, no memset, no device-wide wait.
// Ledger: multi-kernel pipelines = 76-78 regardless of 3/4/5 nodes;
// any in-kernel grid barrier = 86-119 (wait ~25-30us irreducible across
// 3 flavors). So: kernel-boundary sync only, and kill the memset by
// killing the atomics:
//  - K1 "prep8": 8 blocks x 512, each owns 128 rows. Computes A,B
//    (written to global), accumulates Chebyshev moments of its rows
//    block-locally (regs -> LDS atomics, 4-way) and writes a PRIVATE
//    copy M8[b] with plain stores -> no zeroed memory needed.
//    Block 8 builds the C matrix (input-independent DCT-I, fp32).
//  - K2 "combine": R1's proven combine: stage C + Ms(=sum of 8 copies),
//    V=C@Ms in LDS, Chebyshev eval + exact self-term, out = S@W2 + b2.
// Cross-kernel handoff via plain stores/loads is coherent across the
// dispatch boundary (R0/R1-proven; the R7 failure was INTRA-kernel).
// Graph: prep8(9 blocks) -> combine(256 blocks). 2 nodes total.

#define N_E  1024
#define NIN  64
#define HID  128
#define OUTD 64
#define PCH  30      // Chebyshev terms per variable
#define NQ   32      // DCT-I grid: NQ+1 Lobatto points
#define S_CH 5.5f
#define NCPY 8       // private moment copies (= # row blocks in K1)
#define ROWS_PER_BLK (N_E / NCPY)   // 128

static constexpr float INV_S     = 1.0f / 5.5f;
static constexpr float TWO_LOG2E = 2.8853900817779268f; // 2*log2(e)
static constexpr float PI_F      = 3.14159265358979323846f;

__device__ __forceinline__ float tanh_fast(float u) {
  // tanh(u) = 1 - 2/(1+exp2(u*2log2e))
  return 1.0f - 2.0f * __builtin_amdgcn_rcpf(
      1.0f + __builtin_amdgcn_exp2f(u * TWO_LOG2E));
}

// ---- K1: blocks 0..7 compute A,B + block-local moments -> M8[b] (plain
// stores, private copy, no zeroing needed). Block 8 computes C.
__global__ __launch_bounds__(512) void prep8_kernel(
    const float* __restrict__ x, const float* __restrict__ W1,
    const float* __restrict__ b1,
    float* __restrict__ A, float* __restrict__ B,
    float* __restrict__ M8, float* __restrict__ Cg) {
  __shared__ union {
    struct {                         // row blocks: 32 + 15 KB = 47 KB
      float xs[ROWS_PER_BLK][NIN];
      float MsubL[PCH * HID];
    } p1;
    struct {                         // C block: 8.7 KB
      float ctab[NQ + 1];
      float fg[(NQ + 1) * (NQ + 2)];
      float G[PCH * (NQ + 2)];
    } p0;
  } sm;
  const int t = threadIdx.x;
  const int b = blockIdx.x;

  if (b < NCPY) {
    const int r0 = b * ROWS_PER_BLK;
    // stage this block's 128 rows of x (32 KB), zero local moment buffer
    for (int idx = t; idx < ROWS_PER_BLK * NIN; idx += 512)
      ((float*)sm.p1.xs)[idx] = x[r0 * NIN + idx];
    for (int idx = t; idx < PCH * HID; idx += 512) sm.p1.MsubL[idx] = 0.f;
    __syncthreads();

    const int h = t & (HID - 1), sub = t >> 7;   // 4 subs x 32 rows each
    // hoist W1 columns for this h into registers (static idx via unroll)
    float w1a[NIN], w1b[NIN];
    #pragma unroll
    for (int f = 0; f < NIN; ++f) {
      w1a[f] = W1[f * HID + h];                  // coalesced over h
      w1b[f] = W1[(NIN + f) * HID + h];
    }
    const float bb = b1[h];
    float macc[PCH];
    #pragma unroll
    for (int q = 0; q < PCH; ++q) macc[q] = 0.f;

    for (int j = 0; j < ROWS_PER_BLK / 4; ++j) { // 32 rows per thread
      const int r = sub * (ROWS_PER_BLK / 4) + j;
      float aA = 0.f, aB = 0.f;
      #pragma unroll
      for (int f = 0; f < NIN; ++f) {
        const float xv = sm.p1.xs[r][f];         // wave-broadcast
        aA += xv * w1a[f];
        aB += xv * w1b[f];
      }
      aB += bb;
      A[(r0 + r) * HID + h] = aA;                // coalesced over h
      B[(r0 + r) * HID + h] = aB;
      const float c = fminf(fmaxf(aB, -S_CH), S_CH) * INV_S;
      float m0 = 1.f, m1 = c;
      macc[0] += 1.f; macc[1] += c;
      const float c2x = c + c;
      #pragma unroll
      for (int q = 2; q < PCH; ++q) {
        const float m2 = c2x * m1 - m0;
        macc[q] += m2;
        m0 = m1; m1 = m2;
      }
    }
    // block-local reduction: 4 subs per (q,h) via LDS atomics (4-way)
    #pragma unroll
    for (int q = 0; q < PCH; ++q) atomicAdd(&sm.p1.MsubL[q * HID + h], macc[q]);
    __syncthreads();
    // private copy -> global, plain stores (no zero/atomic needed)
    for (int idx = t; idx < PCH * HID; idx += 512)
      M8[b * (PCH * HID) + idx] = sm.p1.MsubL[idx];
  } else {
    // ---- C block: fp32 Chebyshev coefficient matrix via DCT-I ----
    if (t <= NQ) sm.p0.ctab[t] = cosf((float)t * (PI_F / (float)NQ));
    __syncthreads();
    for (int idx = t; idx < (NQ + 1) * (NQ + 1); idx += 512) {
      const int j = idx / (NQ + 1), l = idx % (NQ + 1);
      sm.p0.fg[j * (NQ + 2) + l] =
          tanh_fast(S_CH * (sm.p0.ctab[j] + sm.p0.ctab[l]));
    }
    __syncthreads();
    // G[q][j] = sum_l w_l fg[j][l] cos(q l pi/NQ)  (cos via recurrence)
    for (int idx = t; idx < PCH * (NQ + 1); idx += 512) {
      const int q = idx / (NQ + 1), j = idx % (NQ + 1);
      const float cphi = sm.p0.ctab[q];
      float c0 = 1.f, c1 = cphi;
      float s = 0.5f * sm.p0.fg[j * (NQ + 2) + 0];   // l=0: w=1/2, cos=1
      for (int l = 1; l <= NQ; ++l) {
        const float w = (l == NQ) ? 0.5f : 1.0f;
        s += w * sm.p0.fg[j * (NQ + 2) + l] * c1;
        const float c2 = 2.f * cphi * c1 - c0; c0 = c1; c1 = c2;
      }
      sm.p0.G[q * (NQ + 2) + j] = s;
    }
    __syncthreads();
    // Cg[p][q] = cp cq sum_j w_j G[q][j] cos(p j pi/NQ)
    for (int idx = t; idx < PCH * PCH; idx += 512) {
      const int p = idx / PCH, q = idx % PCH;
      const float cphi = sm.p0.ctab[p];
      float c0 = 1.f, c1 = cphi;
      float s = 0.5f * sm.p0.G[q * (NQ + 2) + 0];
      for (int j = 1; j <= NQ; ++j) {
        const float w = (j == NQ) ? 0.5f : 1.0f;
        s += w * sm.p0.G[q * (NQ + 2) + j] * c1;
        const float c2 = 2.f * cphi * c1 - c0; c0 = c1; c1 = c2;
      }
      const float cp = (p == 0 ? 1.f : 2.f) / (float)NQ;
      const float cq = (q == 0 ? 1.f : 2.f) / (float)NQ;
      Cg[p * PCH + q] = s * cp * cq;
    }
  }
}

// ---- K2: per block (4 rows): stage C + Ms(=sum of 8 copies), V=C@Ms in
// LDS, S[i,h] = (sum_p T_p(a_i) V_p[h] - tanh(A+B))/1023, out = S@W2 + b2.
__global__ __launch_bounds__(512) void combine_kernel(
    const float* __restrict__ A, const float* __restrict__ B,
    const float* __restrict__ M8, const float* __restrict__ Cg,
    const float* __restrict__ W2, const float* __restrict__ b2,
    float* __restrict__ out) {
  __shared__ float Cs[PCH * PCH];        // 3.6 KB
  __shared__ float Ms[PCH * HID];        // 15 KB
  __shared__ float Vl[PCH * HID];        // 15 KB
  __shared__ float Sl[4][HID];
  __shared__ float red[4][2][OUTD];
  const int t = threadIdx.x;
  for (int idx = t; idx < PCH * PCH; idx += 512) Cs[idx] = Cg[idx];
  for (int idx = t; idx < PCH * HID; idx += 512) {
    float s = 0.f;
    #pragma unroll
    for (int c = 0; c < NCPY; ++c) s += M8[c * (PCH * HID) + idx];
    Ms[idx] = s;
  }
  __syncthreads();
  // V = C @ Ms, entirely in LDS (redundant per block; ~115 KFLOP)
  for (int idx = t; idx < PCH * HID; idx += 512) {
    const int p = idx >> 7, hh = idx & (HID - 1);
    float acc = 0.f;
    #pragma unroll
    for (int q = 0; q < PCH; ++q) acc += Cs[p * PCH + q] * Ms[q * HID + hh];
    Vl[idx] = acc;                       // Cs broadcast, Ms stride-1: conflict-free
  }
  __syncthreads();
  const int h = t & (HID - 1), row = t >> 7;
  const int i = blockIdx.x * 4 + row;
  const float ar = A[i * HID + h], br = B[i * HID + h];
  const float a = fminf(fmaxf(ar, -S_CH), S_CH) * INV_S;
  float t0 = 1.f, t1 = a;
  const float a2x = a + a;
  float acc = Vl[h] + a * Vl[HID + h];
  #pragma unroll
  for (int p = 2; p < PCH; ++p) {
    const float t2 = a2x * t1 - t0;
    acc += t2 * Vl[p * HID + h];
    t0 = t1; t1 = t2;
  }
  const float ts = tanh_fast(ar + br);   // exact self term (k==i)
  Sl[row][h] = (acc - ts) * (1.f / (float)(N_E - 1));
  __syncthreads();
  const int o = t & (OUTD - 1), half = (t >> 6) & 1, r2 = t >> 7;
  const int h0 = half * 64;
  float po = 0.f;
  #pragma unroll 16
  for (int hh = 0; hh < 64; ++hh)
    po += Sl[r2][h0 + hh] * W2[(h0 + hh) * OUTD + o];   // coalesced over o, L1-hot
  red[r2][half][o] = po;
  __syncthreads();
  if (t < 4 * OUTD) {
    const int rr = t >> 6, oo = t & (OUTD - 1);
    out[(blockIdx.x * 4 + rr) * OUTD + oo] = red[rr][0][oo] + red[rr][1][oo] + b2[oo];
  }
}

extern "C" void kernel_launch(void* const* d_in, const int* in_sizes, int n_in,
                              void* d_out, int out_size, void* d_ws, size_t ws_size,
                              hipStream_t stream) {
  const float* x  = (const float*)d_in[0];
  const float* W1 = (const float*)d_in[1];
  const float* b1 = (const float*)d_in[2];
  const float* W2 = (const float*)d_in[3];
  const float* b2 = (const float*)d_in[4];
  float* out = (float*)d_out;

  float* A  = (float*)d_ws;               // [N_E][HID]
  float* B  = A + N_E * HID;               // [N_E][HID]
  float* M8 = B + N_E * HID;               // [NCPY][PCH][HID]
  float* Cg = M8 + NCPY * PCH * HID;       // [PCH][PCH]

  prep8_kernel<<<NCPY + 1, 512, 0, stream>>>(x, W1, b1, A, B, M8, Cg);
  combine_kernel<<<N_E / 4, 512, 0, stream>>>(A, B, M8, Cg, W2, b2, out);
}